// Round 18
// baseline (79.943 us; speedup 1.0000x reference)
//
#include <hip/hip_runtime.h>
#include <math.h>

#define EPSF 1e-6f
#define ACH 1024     // anchors per K1 block (4/thread)
#define NBIN 1024    // conf histogram bins
#define CAPB 64      // per-target per-block candidate buffer
#define BIASU 0x4000000000000000ull

struct Part { unsigned long long q0, q1, q2, cand; };

__device__ __forceinline__ double u2d(unsigned long long x){return __longlong_as_double((long long)x);}
__device__ __forceinline__ unsigned long long d2u(double x){return (unsigned long long)__double_as_longlong(x);}

// branchless sorted-insert into descending triple; keys are positive doubles
// (bit62 bias, f32-iou bits in 32..61) so f64 order == u64 order. Keys unique
// (idx field) -> top-3 SET is insertion-order independent.
__device__ __forceinline__ void ins3d(double p, double &q0, double &q1, double &q2) {
  double n0 = fmax(q0,p), x = fmin(q0,p);
  double n1 = fmax(q1,x), y = fmin(q1,x);
  double n2 = fmax(q2,y);
  q0=n0; q1=n1; q2=n2;
}

__device__ __forceinline__ float focal_neg(float c) {
  float pt = 1.f - c;
  float ptc = fminf(fmaxf(pt, EPSF), 1.f - EPSF);
  float om = 1.f - pt;
  return -0.75f * om * om * logf(ptc);
}

// K1: per-(1024-anchor chunk, image). Hot loop: predicate-only per pair —
// m05=max(fma(-.5,d,inter)) [pos iff >=0], m04 likewise [neg iff <0], cand
// bitmask (inter > 0.3d). NO argmax chain, NO in-loop branch/atomics.
// Post-loop: sparse candidate pushes (ffs walk, ~1/thread); sparse argmax
// re-scan only for provisional positives (~1.5%) -> bt for GIoU. Epilogue
// accumulates per-bin negative count+focal hists + pos sums. Plain stores.
__global__ __launch_bounds__(256, 4) void k_fused(
    const float4* __restrict__ anchors, const float4* __restrict__ tboxes,
    const float* __restrict__ conf_pred, const float4* __restrict__ bbox_pred,
    Part* __restrict__ parts, unsigned* __restrict__ ghsC, float* __restrict__ ghsF,
    float* __restrict__ accPosP, float* __restrict__ accBboxP,
    unsigned* __restrict__ cntPosP, unsigned* __restrict__ cntNegP,
    float* __restrict__ out, int A, int T, int nch) {
  __shared__ unsigned long long buf[32][CAPB+1];
  __shared__ unsigned cnt[32];
  __shared__ float4 st[32];
  __shared__ unsigned h[NBIN];
  __shared__ float hf[NBIN];
  __shared__ float sP[256], sB[256];
  __shared__ int cP[256], cN[256];
  int chunk = blockIdx.x, b = blockIdx.y;
  int tid = threadIdx.x;
  int base = chunk * ACH;
  if (tid < 32) cnt[tid] = 0;
  if (tid < T) st[tid] = tboxes[b*T + tid];
  for (int i = tid; i < NBIN; i += 256) { h[i] = 0; hf[i] = 0.f; }
  if (chunk == 4 && b == 0 && tid == 0) out[0] = 0.f;   // K2 runs after
  int i0 = base + tid;
  float4 a0 = anchors[i0], a1 = anchors[i0+256], a2 = anchors[i0+512], a3 = anchors[i0+768];
  float ar0=(a0.z-a0.x)*(a0.w-a0.y), ar1=(a1.z-a1.x)*(a1.w-a1.y);
  float ar2=(a2.z-a2.x)*(a2.w-a2.y), ar3=(a3.z-a3.x)*(a3.w-a3.y);
  __syncthreads();           // cnt/h/hf/st ready
  float m04_0=-1.f, m05_0=-1.f, m04_1=-1.f, m05_1=-1.f;
  float m04_2=-1.f, m05_2=-1.f, m04_3=-1.f, m05_3=-1.f;
  unsigned cm0=0u, cm1=0u, cm2=0u, cm3=0u;

#define PROC(av, arv, m04v, m05v, cmv) { \
    float ix1=fmaxf(av.x,tv.x), iy1=fmaxf(av.y,tv.y); \
    float ix2=fminf(av.z,tv.z), iy2=fminf(av.w,tv.w); \
    float inter=fmaxf(ix2-ix1,0.f)*fmaxf(iy2-iy1,0.f); \
    float u = (arv + ta) - inter, d = u + EPSF;    /* np op order */ \
    m04v = fmaxf(m04v, fmaf(-0.4f, d, inter)); \
    m05v = fmaxf(m05v, fmaf(-0.5f, d, inter)); \
    cmv |= (inter > 0.3f*d) ? bit : 0u; \
  }

  #pragma unroll 4
  for (int tt = 0; tt < T; ++tt) {
    float4 tv = tboxes[b*T + tt];          // uniform load
    float ta = (tv.z-tv.x)*(tv.w-tv.y);
    unsigned bit = 1u << tt;
    PROC(a0, ar0, m04_0, m05_0, cm0)
    PROC(a1, ar1, m04_1, m05_1, cm1)
    PROC(a2, ar2, m04_2, m05_2, cm2)
    PROC(a3, ar3, m04_3, m05_3, cm3)
  }
#undef PROC

  size_t gb = (size_t)b * A;
  float fsum=0.f, bsum=0.f; int cpos=0, cneg=0;
#define EPI(av, arv, m04v, m05v, cmv, idxv) { \
    size_t ia = gb + (size_t)(idxv); \
    float conf = conf_pred[ia]; \
    bool isPos = m05v >= 0.f; \
    bool isNeg = m04v < 0.f; \
    if (isNeg) { \
      int bin = min(NBIN-1,(int)(conf*1024.f)); \
      atomicAdd(&h[bin],1u); \
      atomicAdd(&hf[bin], focal_neg(conf)); \
      cneg++; \
    } \
    unsigned cm = cmv; \
    while (cm) {                           /* sparse candidate pushes */ \
      int tt = __ffs(cm) - 1; cm &= cm - 1; \
      float4 tv = st[tt]; \
      float ta = (tv.z-tv.x)*(tv.w-tv.y); \
      float ix1=fmaxf(av.x,tv.x), iy1=fmaxf(av.y,tv.y); \
      float ix2=fminf(av.z,tv.z), iy2=fminf(av.w,tv.w); \
      float inter=fmaxf(ix2-ix1,0.f)*fmaxf(iy2-iy1,0.f); \
      float d = (arv + ta) - inter + EPSF; \
      float iou = inter * __builtin_amdgcn_rcpf(d);   /* ordering-only key */ \
      unsigned slot = atomicAdd(&cnt[tt], 1u); \
      if (slot < CAPB) \
        buf[tt][slot] = ((unsigned long long)__float_as_uint(iou)<<32) \
                      | (unsigned long long)(0xFFFFFFFFu-(unsigned)(idxv)) | BIASU; \
    } \
    if (isPos) {                           /* sparse argmax re-scan + GIoU */ \
      cpos++; \
      float bn=-1.f, bd=1.f; int bt=0; \
      for (int tt = 0; tt < T; ++tt) { \
        float4 tv = st[tt]; \
        float ta = (tv.z-tv.x)*(tv.w-tv.y); \
        float ix1=fmaxf(av.x,tv.x), iy1=fmaxf(av.y,tv.y); \
        float ix2=fminf(av.z,tv.z), iy2=fminf(av.w,tv.w); \
        float inter=fmaxf(ix2-ix1,0.f)*fmaxf(iy2-iy1,0.f); \
        float u=(arv+ta)-inter, d=u+EPSF; \
        bool gt = inter*bd > bn*d;         /* first-occurrence argmax */ \
        bn=gt?inter:bn; bd=gt?d:bd; bt=gt?tt:bt; \
      } \
      float ptc = fminf(fmaxf(conf, EPSF), 1.f-EPSF); \
      float om = 1.f - conf; \
      fsum += -0.25f * om * om * logf(ptc); \
      float4 pb = bbox_pred[ia]; float4 m = st[bt]; \
      float ix1=fmaxf(pb.x,m.x), iy1=fmaxf(pb.y,m.y); \
      float ix2=fminf(pb.z,m.z), iy2=fminf(pb.w,m.w); \
      float inter=fmaxf(ix2-ix1,0.f)*fmaxf(iy2-iy1,0.f); \
      float aa1=(pb.z-pb.x)*(pb.w-pb.y); \
      float aa2=(m.z-m.x)*(m.w-m.y); \
      float uni = aa1 + aa2 - inter; \
      float iou = inter/(uni+EPSF); \
      float ex1=fminf(pb.x,m.x), ey1=fminf(pb.y,m.y); \
      float ex2=fmaxf(pb.z,m.z), ey2=fmaxf(pb.w,m.w); \
      float enc=(ex2-ex1)*(ey2-ey1); \
      float giou = iou - (enc-uni)/(enc+EPSF); \
      float l1 = fabsf(pb.x-m.x)+fabsf(pb.y-m.y)+fabsf(pb.z-m.z)+fabsf(pb.w-m.w); \
      bsum += (1.f - giou) + 0.125f*l1; \
    } \
  }
  EPI(a0, ar0, m04_0, m05_0, cm0, i0)
  EPI(a1, ar1, m04_1, m05_1, cm1, i0+256)
  EPI(a2, ar2, m04_2, m05_2, cm2, i0+512)
  EPI(a3, ar3, m04_3, m05_3, cm3, i0+768)
#undef EPI

  sP[tid]=fsum; sB[tid]=bsum; cP[tid]=cpos; cN[tid]=cneg;
  __syncthreads();
  for (int s=128;s>0;s>>=1) {
    if (tid<s){ sP[tid]+=sP[tid+s]; sB[tid]+=sB[tid+s]; cP[tid]+=cP[tid+s]; cN[tid]+=cN[tid+s]; }
    __syncthreads();
  }
  if (tid == 0) {
    int pidx = b*nch + chunk;
    accPosP[pidx]  = sP[0];
    accBboxP[pidx] = sB[0];
    cntPosP[pidx]  = (unsigned)cP[0];
    cntNegP[pidx]  = (unsigned)cN[0];
  }
  for (int i = tid; i < NBIN; i += 256) {
    ghsC[(size_t)(b*nch + chunk)*NBIN + i] = h[i];
    ghsF[(size_t)(b*nch + chunk)*NBIN + i] = hf[i];
  }

  const double BIASD = u2d(BIASU);
  if (tid < 32 && tid < T) {               // per-target merge
    unsigned n = cnt[tid];
    if (n <= CAPB) {
      double q0=BIASD, q1=BIASD, q2=BIASD;
      for (unsigned j = 0; j < n; ++j) ins3d(u2d(buf[tid][j]), q0,q1,q2);
      Part p; p.q0=d2u(q0); p.q1=d2u(q1); p.q2=d2u(q2); p.cand=n;
      parts[(b*T+tid)*nch+chunk] = p;
    }
  }
  if (tid < 64) {                          // exact overflow fallback (~never)
    unsigned long long ovf = __ballot(tid < T && cnt[tid] > CAPB);
    while (ovf) {
      int t = __ffsll(ovf) - 1;
      ovf &= ovf - 1;
      float4 tv = tboxes[b*T + t];
      float ta = (tv.z-tv.x)*(tv.w-tv.y);
      double q0=BIASD, q1=BIASD, q2=BIASD;
      for (int j = 0; j < ACH; j += 64) {
        int idx = base + j + tid;
        float4 an = anchors[idx];
        float aa = (an.z-an.x)*(an.w-an.y);
        float ix1=fmaxf(an.x,tv.x), iy1=fmaxf(an.y,tv.y);
        float ix2=fminf(an.z,tv.z), iy2=fminf(an.w,tv.w);
        float inter=fmaxf(ix2-ix1,0.f)*fmaxf(iy2-iy1,0.f);
        float d = (aa+ta)-inter + EPSF;
        if (inter > 0.3f*d) {
          float iou = inter / d;
          unsigned long long pk = ((unsigned long long)__float_as_uint(iou)<<32)
                                | (unsigned long long)(0xFFFFFFFFu-(unsigned)idx) | BIASU;
          ins3d(u2d(pk), q0,q1,q2);
        }
      }
      for (int s=1;s<64;s<<=1) {
        double r0=__shfl_xor(q0,s,64), r1=__shfl_xor(q1,s,64), r2=__shfl_xor(q2,s,64);
        ins3d(r0,q0,q1,q2); ins3d(r1,q0,q1,q2); ins3d(r2,q0,q1,q2);
      }
      if (tid == 0) {
        Part p; p.q0=d2u(q0); p.q1=d2u(q1); p.q2=d2u(q2); p.cand=cnt[t];
        parts[(b*T+t)*nch+chunk] = p;
      }
    }
  }
}

// K2 (k_tail): one block per image, 1024 threads. No per-anchor streaming.
// A parts-merge; B cand==0 fallback; C reduce count+focal hist slices;
// D forced corrections using K1's EXACT fma predicates (m05/m04) so the
//   already-pos / was-negative decisions match K1 bit-for-bit;
// E partials reduce; F suffix count-scan + hist-based negSum.
__global__ __launch_bounds__(1024) void k_tail(
    const float4* __restrict__ anchors, const float4* __restrict__ tboxes,
    const Part* __restrict__ parts,
    const float* __restrict__ conf_pred, const float4* __restrict__ bbox_pred,
    const unsigned* __restrict__ ghsC, const float* __restrict__ ghsF,
    const float* __restrict__ accPosP, const float* __restrict__ accBboxP,
    const unsigned* __restrict__ cntPosP, const unsigned* __restrict__ cntNegP,
    float* __restrict__ out, int A, int T, int nch, int B) {
  __shared__ double s0[1024], s1[1024], s2[1024];
  __shared__ unsigned scnt[1024];
  __shared__ unsigned hhC[NBIN];
  __shared__ float hhF[NBIN];
  __shared__ unsigned sc[NBIN];
  __shared__ float sredf[1024];
  __shared__ float4 st[32];
  __shared__ int flist[160];
  __shared__ unsigned fcnt;
  __shared__ float corrP, corrB;
  __shared__ unsigned corrNP, corrNN;
  __shared__ float accPos_s, accBbox_s;
  __shared__ unsigned cntPos_s, cntNeg_s;
  __shared__ int sSelB, sKrem;
  int b = blockIdx.x, tid = threadIdx.x;
  const double BIASD = u2d(BIASU);
  if (tid < T) st[tid] = tboxes[b*T + tid];
  if (tid == 0) { fcnt = 0; corrP = 0.f; corrB = 0.f; corrNP = 0u; corrNN = 0u; }
  __syncthreads();

  // ---- Phase A: parts-merge ----
  {
    int t = tid & 31, g = tid >> 5;
    double q0=BIASD, q1=BIASD, q2=BIASD;
    unsigned long long cand = 0;
    if (t < T) {
      const Part* pp = parts + (size_t)(b*T + t)*nch;
      for (int c = g; c < nch; c += 32) {
        Part p = pp[c];
        ins3d(u2d(p.q0),q0,q1,q2); ins3d(u2d(p.q1),q0,q1,q2); ins3d(u2d(p.q2),q0,q1,q2);
        cand += p.cand;
      }
    }
    s0[tid]=q0; s1[tid]=q1; s2[tid]=q2; scnt[tid]=(unsigned)cand;
    __syncthreads();
    for (int s=512; s>=32; s>>=1) {        // partners share t
      if (tid < s) {
        double a0=s0[tid], a1=s1[tid], a2=s2[tid];
        ins3d(s0[tid+s],a0,a1,a2); ins3d(s1[tid+s],a0,a1,a2); ins3d(s2[tid+s],a0,a1,a2);
        s0[tid]=a0; s1[tid]=a1; s2[tid]=a2; scnt[tid]+=scnt[tid+s];
      }
      __syncthreads();
    }
    if (tid < 32 && tid < T) {
      unsigned cd = scnt[tid];
      if (cd > 0) {
        int kt = cd > 3 ? 3 : (int)cd;
        unsigned long long tp[3] = {d2u(s0[tid]), d2u(s1[tid]), d2u(s2[tid])};
        for (int j = 0; j < kt; ++j) {
          int idx = (int)(0xFFFFFFFFu - (unsigned)(tp[j] & 0xFFFFFFFFull));
          flist[atomicAdd(&fcnt, 1u)] = idx;
        }
      }
    }
    __syncthreads();
  }
  // ---- Phase B: cand==0 fallback (~never) ----
  for (int t2 = 0; t2 < T; ++t2) {
    if (scnt[t2] == 0) {
      float4 tv = st[t2];
      float ta = (tv.z-tv.x)*(tv.w-tv.y);
      double m = BIASD;
      for (int a = tid; a < A; a += 1024) {
        float4 an = anchors[a];
        float aa = (an.z-an.x)*(an.w-an.y);
        float ix1=fmaxf(an.x,tv.x), iy1=fmaxf(an.y,tv.y);
        float ix2=fminf(an.z,tv.z), iy2=fminf(an.w,tv.w);
        float inter=fmaxf(ix2-ix1,0.f)*fmaxf(iy2-iy1,0.f);
        float iou = inter / ((aa+ta)-inter + EPSF);
        unsigned long long pk = ((unsigned long long)__float_as_uint(iou)<<32)
                              | (unsigned long long)(0xFFFFFFFFu-(unsigned)a) | BIASU;
        m = fmax(m, u2d(pk));
      }
      s0[tid] = m;
      __syncthreads();
      for (int s=512;s>0;s>>=1) { if (tid<s) s0[tid]=fmax(s0[tid],s0[tid+s]); __syncthreads(); }
      if (tid == 0) {
        int idx = (int)(0xFFFFFFFFu - (unsigned)(d2u(s0[0]) & 0xFFFFFFFFull));
        flist[atomicAdd(&fcnt, 1u)] = idx;
      }
      __syncthreads();
    }
  }
  // ---- Phase C: reduce hist slices (bin = tid; 64 coalesced slices each) ----
  {
    unsigned accC = 0; float accF = 0.f;
    const unsigned* bc = ghsC + (size_t)b*nch*NBIN + tid;
    const float*    bf = ghsF + (size_t)b*nch*NBIN + tid;
    #pragma unroll 16
    for (int c = 0; c < 64; ++c) {         // nch==64
      accC += bc[(size_t)c*NBIN];
      accF += bf[(size_t)c*NBIN];
    }
    hhC[tid] = accC; hhF[tid] = accF;
  }
  __syncthreads();
  // ---- Phase D: forced corrections (K1-identical fma predicates) ----
  {
    unsigned n = min(fcnt, 160u);
    size_t gb = (size_t)b * A;
    for (unsigned i = tid; i < n; i += 1024) {
      int idx = flist[i];
      bool dup = false;
      for (unsigned j = 0; j < i; ++j) if (flist[j] == idx) { dup = true; break; }
      if (dup) continue;
      float4 an = anchors[idx];
      float ar = (an.z-an.x)*(an.w-an.y);
      float m04=-1.f, m05=-1.f;
      float bn=-1.f, bd=1.f; int bt=0;
      for (int tt = 0; tt < T; ++tt) {     // same ops/order as K1 -> same bits
        float4 tv = st[tt];
        float ta = (tv.z-tv.x)*(tv.w-tv.y);
        float ix1=fmaxf(an.x,tv.x), iy1=fmaxf(an.y,tv.y);
        float ix2=fminf(an.z,tv.z), iy2=fminf(an.w,tv.w);
        float inter=fmaxf(ix2-ix1,0.f)*fmaxf(iy2-iy1,0.f);
        float u=(ar+ta)-inter, d=u+EPSF;
        m04 = fmaxf(m04, fmaf(-0.4f, d, inter));
        m05 = fmaxf(m05, fmaf(-0.5f, d, inter));
        bool gt = inter*bd > bn*d;
        bn=gt?inter:bn; bd=gt?d:bd; bt=gt?tt:bt;
      }
      if (m05 < 0.f) {                     // not already pos in K1
        size_t ia = gb + (size_t)idx;
        float conf = conf_pred[ia];
        float ptc = fminf(fmaxf(conf, EPSF), 1.f-EPSF);
        float om = 1.f - conf;
        atomicAdd(&corrP, -0.25f*om*om*logf(ptc));
        atomicAdd(&corrNP, 1u);
        float4 pb = bbox_pred[ia]; float4 m = st[bt];
        float ix1=fmaxf(pb.x,m.x), iy1=fmaxf(pb.y,m.y);
        float ix2=fminf(pb.z,m.z), iy2=fminf(pb.w,m.w);
        float inter=fmaxf(ix2-ix1,0.f)*fmaxf(iy2-iy1,0.f);
        float aa1=(pb.z-pb.x)*(pb.w-pb.y);
        float aa2=(m.z-m.x)*(m.w-m.y);
        float uni = aa1 + aa2 - inter;
        float iou = inter/(uni+EPSF);
        float ex1=fminf(pb.x,m.x), ey1=fminf(pb.y,m.y);
        float ex2=fmaxf(pb.z,m.z), ey2=fmaxf(pb.w,m.w);
        float enc=(ex2-ex1)*(ey2-ey1);
        float giou = iou - (enc-uni)/(enc+EPSF);
        float l1 = fabsf(pb.x-m.x)+fabsf(pb.y-m.y)+fabsf(pb.z-m.z)+fabsf(pb.w-m.w);
        atomicAdd(&corrB, (1.f - giou) + 0.125f*l1);
        if (m04 < 0.f) {                   // was counted negative in K1
          int bin = min(NBIN-1, (int)(conf*1024.f));
          atomicSub(&hhC[bin], 1u);
          atomicAdd(&hhF[bin], -focal_neg(conf));
          atomicAdd(&corrNN, 1u);
        }
      }
    }
  }
  __syncthreads();
  // ---- Phase E: partials wave-reduce (wave 0) ----
  if (tid < 64) {
    float ap = 0.f, ab = 0.f; unsigned np = 0, nn = 0;
    if (tid < nch) {
      int pidx = b*nch + tid;
      ap = accPosP[pidx]; ab = accBboxP[pidx];
      np = cntPosP[pidx]; nn = cntNegP[pidx];
    }
    for (int s = 1; s < 64; s <<= 1) {
      ap += __shfl_xor(ap, s, 64); ab += __shfl_xor(ab, s, 64);
      np += __shfl_xor(np, s, 64); nn += __shfl_xor(nn, s, 64);
    }
    if (tid == 0) {
      accPos_s  = ap + corrP;
      accBbox_s = ab + corrB;
      cntPos_s  = np + corrNP;
      cntNeg_s  = nn - corrNN;
    }
  }
  __syncthreads();
  // ---- Phase F: suffix count-scan -> selB/krem; hist-based negSum ----
  int np = (int)cntPos_s, nn = (int)cntNeg_s;
  int ratio = (np>0) ? min(3, A/np) : 0;
  int k = min(ratio*np, nn);
  float negSum = 0.f;
  if (k > 0) {
    sc[tid] = hhC[NBIN-1-tid];
    __syncthreads();
    for (int off=1; off<NBIN; off<<=1) {    // inclusive scan of reversed hist
      unsigned v = (tid >= off) ? sc[tid-off] : 0u;
      __syncthreads();
      sc[tid] += v;
      __syncthreads();
    }
    {
      unsigned Sb  = sc[NBIN-1-tid];
      unsigned Snx = (tid == NBIN-1) ? 0u : sc[NBIN-2-tid];
      if (Sb >= (unsigned)k && Snx < (unsigned)k) { sSelB = tid; sKrem = k - (int)Snx; }
    }
    __syncthreads();
    int selB = sSelB, krem = sKrem;
    sredf[tid] = (tid > selB) ? hhF[tid] : 0.f;
    __syncthreads();
    for (int s=512;s>0;s>>=1){ if(tid<s) sredf[tid]+=sredf[tid+s]; __syncthreads(); }
    float cutMean = hhF[selB] / (float)max(hhC[selB], 1u);  // hhC[selB] >= krem >= 1
    negSum = sredf[0] + (float)krem * cutMean;
  }
  if (tid==0) {
    float confL = (accPos_s + negSum) / (float)max(np + k, 1);
    float bboxL = accBbox_s / (float)(np > 0 ? np : 1);
    atomicAdd(out, (confL + bboxL) / (float)B);   // out zeroed by K1
  }
}

extern "C" void kernel_launch(void* const* d_in, const int* in_sizes, int n_in,
                              void* d_out, int out_size, void* d_ws, size_t ws_size,
                              hipStream_t stream) {
  const float4* bbox_pred = (const float4*)d_in[0];
  const float*  conf_pred = (const float*)d_in[1];
  const float4* anchors   = (const float4*)d_in[2];
  const float4* tboxes    = (const float4*)d_in[3];
  float* out = (float*)d_out;

  int A = in_sizes[2] / 4;          // 65536
  int B = in_sizes[1] / A;          // 16
  int T = in_sizes[3] / (4 * B);    // 32
  int nch = A / ACH;                // 64

  // ws: parts Part[B*T*nch] | ghsC u32[B*nch*NBIN] | ghsF f32[B*nch*NBIN] |
  //     accPosP f32[B*nch] | accBboxP f32[B*nch] | cntPosP u32[B*nch] | cntNegP u32[B*nch]
  Part* parts = (Part*)d_ws;
  unsigned* ghsC = (unsigned*)(parts + (size_t)B*T*nch);
  float* ghsF = (float*)(ghsC + (size_t)B*nch*NBIN);
  float* accPosP  = (float*)(ghsF + (size_t)B*nch*NBIN);
  float* accBboxP = accPosP + (size_t)B*nch;
  unsigned* cntPosP = (unsigned*)(accBboxP + (size_t)B*nch);
  unsigned* cntNegP = cntPosP + (size_t)B*nch;

  dim3 gf((unsigned)nch, (unsigned)B);
  k_fused<<<gf, 256, 0, stream>>>(anchors, tboxes, conf_pred, bbox_pred,
                                  parts, ghsC, ghsF,
                                  accPosP, accBboxP, cntPosP, cntNegP, out, A, T, nch);

  k_tail<<<B, 1024, 0, stream>>>(anchors, tboxes, parts, conf_pred, bbox_pred,
                                 ghsC, ghsF, accPosP, accBboxP, cntPosP, cntNegP,
                                 out, A, T, nch, B);
}

// Round 21
// 63.776 us; speedup vs baseline: 1.2535x; 1.2535x over previous
//
#include <hip/hip_runtime.h>
#include <math.h>

#define EPSF 1e-6f
#define ACH 1024     // anchors per K1 block (4/thread)
#define NBIN 1024    // conf histogram bins
#define CAPB 64      // per-target per-block candidate buffer
#define BIASU 0x4000000000000000ull

struct Part { unsigned long long q0, q1, q2, cand; };

__device__ __forceinline__ double u2d(unsigned long long x){return __longlong_as_double((long long)x);}
__device__ __forceinline__ unsigned long long d2u(double x){return (unsigned long long)__double_as_longlong(x);}

// branchless sorted-insert into descending triple; keys are positive doubles
// (bit62 bias, f32-iou bits in 32..61) so f64 order == u64 order. Keys unique
// (idx field) -> top-3 SET is insertion-order independent.
__device__ __forceinline__ void ins3d(double p, double &q0, double &q1, double &q2) {
  double n0 = fmax(q0,p), x = fmin(q0,p);
  double n1 = fmax(q1,x), y = fmin(q1,x);
  double n2 = fmax(q2,y);
  q0=n0; q1=n1; q2=n2;
}

__device__ __forceinline__ float focal_neg(float c) {
  float pt = 1.f - c;
  float ptc = fminf(fmaxf(pt, EPSF), 1.f - EPSF);
  float om = 1.f - pt;
  return -0.75f * om * om * logf(ptc);
}

// K1: per-(1024-anchor chunk, image). Hot loop = r17's cross-mult argmax
// (bt free, no re-scan) BUT candidate test is a branchless bitmask; pushes
// deferred to a sparse ffs walk in the epilogue (r18-validated). No in-loop
// branches or LDS atomics. Epilogue: classification from mi=bn/bd (np-bitwise),
// per-bin negative count+focal hists, pos focal+GIoU. Plain stores.
__global__ __launch_bounds__(256, 4) void k_fused(
    const float4* __restrict__ anchors, const float4* __restrict__ tboxes,
    const float* __restrict__ conf_pred, const float4* __restrict__ bbox_pred,
    Part* __restrict__ parts, unsigned* __restrict__ ghsC, float* __restrict__ ghsF,
    float* __restrict__ accPosP, float* __restrict__ accBboxP,
    unsigned* __restrict__ cntPosP, unsigned* __restrict__ cntNegP,
    float* __restrict__ out, int A, int T, int nch) {
  __shared__ unsigned long long buf[32][CAPB+1];
  __shared__ unsigned cnt[32];
  __shared__ float4 st[32];
  __shared__ unsigned h[NBIN];
  __shared__ float hf[NBIN];
  __shared__ float sP[256], sB[256];
  __shared__ int cP[256], cN[256];
  int chunk = blockIdx.x, b = blockIdx.y;
  int tid = threadIdx.x;
  int base = chunk * ACH;
  if (tid < 32) cnt[tid] = 0;
  if (tid < T) st[tid] = tboxes[b*T + tid];
  for (int i = tid; i < NBIN; i += 256) { h[i] = 0; hf[i] = 0.f; }
  if (chunk == 4 && b == 0 && tid == 0) out[0] = 0.f;   // K2 runs after
  int i0 = base + tid;
  float4 a0 = anchors[i0], a1 = anchors[i0+256], a2 = anchors[i0+512], a3 = anchors[i0+768];
  float ar0=(a0.z-a0.x)*(a0.w-a0.y), ar1=(a1.z-a1.x)*(a1.w-a1.y);
  float ar2=(a2.z-a2.x)*(a2.w-a2.y), ar3=(a3.z-a3.x)*(a3.w-a3.y);
  __syncthreads();           // cnt/h/hf/st ready
  float bn0=-1.f,bd0=1.f, bn1=-1.f,bd1=1.f, bn2=-1.f,bd2=1.f, bn3=-1.f,bd3=1.f;
  int bt0=0, bt1=0, bt2=0, bt3=0;
  unsigned cm0=0u, cm1=0u, cm2=0u, cm3=0u;

#define PROC(av, arv, bnv, bdv, btv, cmv) { \
    float ix1=fmaxf(av.x,tv.x), iy1=fmaxf(av.y,tv.y); \
    float ix2=fminf(av.z,tv.z), iy2=fminf(av.w,tv.w); \
    float inter=fmaxf(ix2-ix1,0.f)*fmaxf(iy2-iy1,0.f); \
    float u = (arv + ta) - inter, d = u + EPSF;    /* np op order */ \
    bool gt = inter*bdv > bnv*d;                   /* first-occurrence argmax */ \
    bnv=gt?inter:bnv; bdv=gt?d:bdv; btv=gt?tt:btv; \
    cmv |= (inter > 0.3f*d) ? bit : 0u;            /* == iou>0.3 up to 1ulp */ \
  }

  #pragma unroll 4
  for (int tt = 0; tt < T; ++tt) {
    float4 tv = tboxes[b*T + tt];          // uniform load
    float ta = (tv.z-tv.x)*(tv.w-tv.y);
    unsigned bit = 1u << tt;
    PROC(a0, ar0, bn0, bd0, bt0, cm0)
    PROC(a1, ar1, bn1, bd1, bt1, cm1)
    PROC(a2, ar2, bn2, bd2, bt2, cm2)
    PROC(a3, ar3, bn3, bd3, bt3, cm3)
  }
#undef PROC

  size_t gb = (size_t)b * A;
  float fsum=0.f, bsum=0.f; int cpos=0, cneg=0;
#define EPI(av, arv, bnv, bdv, btv, cmv, idxv) { \
    float mi = bnv/bdv;                     /* precise, np-bitwise */ \
    size_t ia = gb + (size_t)(idxv); \
    float conf = conf_pred[ia]; \
    bool isPos = mi >= 0.5f; \
    bool isNeg = mi < 0.4f; \
    if (isNeg) { \
      int bin = min(NBIN-1,(int)(conf*1024.f)); \
      atomicAdd(&h[bin],1u); \
      atomicAdd(&hf[bin], focal_neg(conf)); \
      cneg++; \
    } \
    unsigned cm = cmv; \
    while (cm) {                            /* sparse pushes (~1.3/thread) */ \
      int tt = __ffs(cm) - 1; cm &= cm - 1; \
      float4 tv = st[tt]; \
      float ta = (tv.z-tv.x)*(tv.w-tv.y); \
      float ix1=fmaxf(av.x,tv.x), iy1=fmaxf(av.y,tv.y); \
      float ix2=fminf(av.z,tv.z), iy2=fminf(av.w,tv.w); \
      float inter=fmaxf(ix2-ix1,0.f)*fmaxf(iy2-iy1,0.f); \
      float d = (arv + ta) - inter + EPSF; \
      float iou = inter * __builtin_amdgcn_rcpf(d);   /* ordering-only key */ \
      unsigned slot = atomicAdd(&cnt[tt], 1u); \
      if (slot < CAPB) \
        buf[tt][slot] = ((unsigned long long)__float_as_uint(iou)<<32) \
                      | (unsigned long long)(0xFFFFFFFFu-(unsigned)(idxv)) | BIASU; \
    } \
    if (isPos) { \
      cpos++; \
      float ptc = fminf(fmaxf(conf, EPSF), 1.f-EPSF); \
      float om = 1.f - conf; \
      fsum += -0.25f * om * om * logf(ptc); \
      float4 pb = bbox_pred[ia]; float4 m = st[btv]; \
      float ix1=fmaxf(pb.x,m.x), iy1=fmaxf(pb.y,m.y); \
      float ix2=fminf(pb.z,m.z), iy2=fminf(pb.w,m.w); \
      float inter=fmaxf(ix2-ix1,0.f)*fmaxf(iy2-iy1,0.f); \
      float aa1=(pb.z-pb.x)*(pb.w-pb.y); \
      float aa2=(m.z-m.x)*(m.w-m.y); \
      float uni = aa1 + aa2 - inter; \
      float iou = inter/(uni+EPSF); \
      float ex1=fminf(pb.x,m.x), ey1=fminf(pb.y,m.y); \
      float ex2=fmaxf(pb.z,m.z), ey2=fmaxf(pb.w,m.w); \
      float enc=(ex2-ex1)*(ey2-ey1); \
      float giou = iou - (enc-uni)/(enc+EPSF); \
      float l1 = fabsf(pb.x-m.x)+fabsf(pb.y-m.y)+fabsf(pb.z-m.z)+fabsf(pb.w-m.w); \
      bsum += (1.f - giou) + 0.125f*l1; \
    } \
  }
  EPI(a0, ar0, bn0, bd0, bt0, cm0, i0)
  EPI(a1, ar1, bn1, bd1, bt1, cm1, i0+256)
  EPI(a2, ar2, bn2, bd2, bt2, cm2, i0+512)
  EPI(a3, ar3, bn3, bd3, bt3, cm3, i0+768)
#undef EPI

  sP[tid]=fsum; sB[tid]=bsum; cP[tid]=cpos; cN[tid]=cneg;
  __syncthreads();
  for (int s=128;s>0;s>>=1) {
    if (tid<s){ sP[tid]+=sP[tid+s]; sB[tid]+=sB[tid+s]; cP[tid]+=cP[tid+s]; cN[tid]+=cN[tid+s]; }
    __syncthreads();
  }
  if (tid == 0) {
    int pidx = b*nch + chunk;
    accPosP[pidx]  = sP[0];
    accBboxP[pidx] = sB[0];
    cntPosP[pidx]  = (unsigned)cP[0];
    cntNegP[pidx]  = (unsigned)cN[0];
  }
  for (int i = tid; i < NBIN; i += 256) {
    ghsC[(size_t)(b*nch + chunk)*NBIN + i] = h[i];
    ghsF[(size_t)(b*nch + chunk)*NBIN + i] = hf[i];
  }

  const double BIASD = u2d(BIASU);
  if (tid < 32 && tid < T) {               // per-target merge
    unsigned n = cnt[tid];
    if (n <= CAPB) {
      double q0=BIASD, q1=BIASD, q2=BIASD;
      for (unsigned j = 0; j < n; ++j) ins3d(u2d(buf[tid][j]), q0,q1,q2);
      Part p; p.q0=d2u(q0); p.q1=d2u(q1); p.q2=d2u(q2); p.cand=n;
      parts[(b*T+tid)*nch+chunk] = p;
    }
  }
  if (tid < 64) {                          // exact overflow fallback (~never)
    unsigned long long ovf = __ballot(tid < T && cnt[tid] > CAPB);
    while (ovf) {
      int t = __ffsll(ovf) - 1;
      ovf &= ovf - 1;
      float4 tv = tboxes[b*T + t];
      float ta = (tv.z-tv.x)*(tv.w-tv.y);
      double q0=BIASD, q1=BIASD, q2=BIASD;
      for (int j = 0; j < ACH; j += 64) {
        int idx = base + j + tid;
        float4 an = anchors[idx];
        float aa = (an.z-an.x)*(an.w-an.y);
        float ix1=fmaxf(an.x,tv.x), iy1=fmaxf(an.y,tv.y);
        float ix2=fminf(an.z,tv.z), iy2=fminf(an.w,tv.w);
        float inter=fmaxf(ix2-ix1,0.f)*fmaxf(iy2-iy1,0.f);
        float d = (aa+ta)-inter + EPSF;
        if (inter > 0.3f*d) {
          float iou = inter / d;
          unsigned long long pk = ((unsigned long long)__float_as_uint(iou)<<32)
                                | (unsigned long long)(0xFFFFFFFFu-(unsigned)idx) | BIASU;
          ins3d(u2d(pk), q0,q1,q2);
        }
      }
      for (int s=1;s<64;s<<=1) {
        double r0=__shfl_xor(q0,s,64), r1=__shfl_xor(q1,s,64), r2=__shfl_xor(q2,s,64);
        ins3d(r0,q0,q1,q2); ins3d(r1,q0,q1,q2); ins3d(r2,q0,q1,q2);
      }
      if (tid == 0) {
        Part p; p.q0=d2u(q0); p.q1=d2u(q1); p.q2=d2u(q2); p.cand=cnt[t];
        parts[(b*T+t)*nch+chunk] = p;
      }
    }
  }
}

// K2 (k_tail): one block per image, 1024 threads. No per-anchor streaming.
// A parts-merge; B cand==0 fallback; C reduce count+focal hist slices;
// D forced corrections (cross-mult mi, K1-bitwise); E partials reduce;
// F suffix count-scan + hist-based negSum.
__global__ __launch_bounds__(1024) void k_tail(
    const float4* __restrict__ anchors, const float4* __restrict__ tboxes,
    const Part* __restrict__ parts,
    const float* __restrict__ conf_pred, const float4* __restrict__ bbox_pred,
    const unsigned* __restrict__ ghsC, const float* __restrict__ ghsF,
    const float* __restrict__ accPosP, const float* __restrict__ accBboxP,
    const unsigned* __restrict__ cntPosP, const unsigned* __restrict__ cntNegP,
    float* __restrict__ out, int A, int T, int nch, int B) {
  __shared__ double s0[1024], s1[1024], s2[1024];
  __shared__ unsigned scnt[1024];
  __shared__ unsigned hhC[NBIN];
  __shared__ float hhF[NBIN];
  __shared__ unsigned sc[NBIN];
  __shared__ float sredf[1024];
  __shared__ float4 st[32];
  __shared__ int flist[160];
  __shared__ unsigned fcnt;
  __shared__ float corrP, corrB;
  __shared__ unsigned corrNP, corrNN;
  __shared__ float accPos_s, accBbox_s;
  __shared__ unsigned cntPos_s, cntNeg_s;
  __shared__ int sSelB, sKrem;
  int b = blockIdx.x, tid = threadIdx.x;
  const double BIASD = u2d(BIASU);
  if (tid < T) st[tid] = tboxes[b*T + tid];
  if (tid == 0) { fcnt = 0; corrP = 0.f; corrB = 0.f; corrNP = 0u; corrNN = 0u; }
  __syncthreads();

  // ---- Phase A: parts-merge ----
  {
    int t = tid & 31, g = tid >> 5;
    double q0=BIASD, q1=BIASD, q2=BIASD;
    unsigned long long cand = 0;
    if (t < T) {
      const Part* pp = parts + (size_t)(b*T + t)*nch;
      for (int c = g; c < nch; c += 32) {
        Part p = pp[c];
        ins3d(u2d(p.q0),q0,q1,q2); ins3d(u2d(p.q1),q0,q1,q2); ins3d(u2d(p.q2),q0,q1,q2);
        cand += p.cand;
      }
    }
    s0[tid]=q0; s1[tid]=q1; s2[tid]=q2; scnt[tid]=(unsigned)cand;
    __syncthreads();
    for (int s=512; s>=32; s>>=1) {        // partners share t
      if (tid < s) {
        double a0=s0[tid], a1=s1[tid], a2=s2[tid];
        ins3d(s0[tid+s],a0,a1,a2); ins3d(s1[tid+s],a0,a1,a2); ins3d(s2[tid+s],a0,a1,a2);
        s0[tid]=a0; s1[tid]=a1; s2[tid]=a2; scnt[tid]+=scnt[tid+s];
      }
      __syncthreads();
    }
    if (tid < 32 && tid < T) {
      unsigned cd = scnt[tid];
      if (cd > 0) {
        int kt = cd > 3 ? 3 : (int)cd;
        unsigned long long tp[3] = {d2u(s0[tid]), d2u(s1[tid]), d2u(s2[tid])};
        for (int j = 0; j < kt; ++j) {
          int idx = (int)(0xFFFFFFFFu - (unsigned)(tp[j] & 0xFFFFFFFFull));
          flist[atomicAdd(&fcnt, 1u)] = idx;
        }
      }
    }
    __syncthreads();
  }
  // ---- Phase B: cand==0 fallback (~never; scnt[t2] block-uniform) ----
  for (int t2 = 0; t2 < T; ++t2) {
    if (scnt[t2] == 0) {
      float4 tv = st[t2];
      float ta = (tv.z-tv.x)*(tv.w-tv.y);
      double m = BIASD;
      for (int a = tid; a < A; a += 1024) {
        float4 an = anchors[a];
        float aa = (an.z-an.x)*(an.w-an.y);
        float ix1=fmaxf(an.x,tv.x), iy1=fmaxf(an.y,tv.y);
        float ix2=fminf(an.z,tv.z), iy2=fminf(an.w,tv.w);
        float inter=fmaxf(ix2-ix1,0.f)*fmaxf(iy2-iy1,0.f);
        float iou = inter / ((aa+ta)-inter + EPSF);
        unsigned long long pk = ((unsigned long long)__float_as_uint(iou)<<32)
                              | (unsigned long long)(0xFFFFFFFFu-(unsigned)a) | BIASU;
        m = fmax(m, u2d(pk));
      }
      s0[tid] = m;
      __syncthreads();
      for (int s=512;s>0;s>>=1) { if (tid<s) s0[tid]=fmax(s0[tid],s0[tid+s]); __syncthreads(); }
      if (tid == 0) {
        int idx = (int)(0xFFFFFFFFu - (unsigned)(d2u(s0[0]) & 0xFFFFFFFFull));
        flist[atomicAdd(&fcnt, 1u)] = idx;
      }
      __syncthreads();
    }
  }
  // ---- Phase C: reduce hist slices (bin = tid; 64 coalesced slices each) ----
  {
    unsigned accC = 0; float accF = 0.f;
    const unsigned* bc = ghsC + (size_t)b*nch*NBIN + tid;
    const float*    bf = ghsF + (size_t)b*nch*NBIN + tid;
    #pragma unroll 16
    for (int c = 0; c < 64; ++c) {         // nch==64
      accC += bc[(size_t)c*NBIN];
      accF += bf[(size_t)c*NBIN];
    }
    hhC[tid] = accC; hhF[tid] = accF;
  }
  __syncthreads();
  // ---- Phase D: forced corrections (K1-identical cross-mult argmax) ----
  {
    unsigned n = min(fcnt, 160u);
    size_t gb = (size_t)b * A;
    for (unsigned i = tid; i < n; i += 1024) {
      int idx = flist[i];
      bool dup = false;
      for (unsigned j = 0; j < i; ++j) if (flist[j] == idx) { dup = true; break; }
      if (dup) continue;
      float4 an = anchors[idx];
      float ar = (an.z-an.x)*(an.w-an.y);
      float bn=-1.f, bd=1.f; int bt=0;
      for (int tt = 0; tt < T; ++tt) {     // same ops/order as K1 -> same bits
        float4 tv = st[tt];
        float ta = (tv.z-tv.x)*(tv.w-tv.y);
        float ix1=fmaxf(an.x,tv.x), iy1=fmaxf(an.y,tv.y);
        float ix2=fminf(an.z,tv.z), iy2=fminf(an.w,tv.w);
        float inter=fmaxf(ix2-ix1,0.f)*fmaxf(iy2-iy1,0.f);
        float u=(ar+ta)-inter, d=u+EPSF;
        bool gt = inter*bd > bn*d;
        bn=gt?inter:bn; bd=gt?d:bd; bt=gt?tt:bt;
      }
      float mi = bn/bd;
      if (mi < 0.5f) {                     // not already pos in K1
        size_t ia = gb + (size_t)idx;
        float conf = conf_pred[ia];
        float ptc = fminf(fmaxf(conf, EPSF), 1.f-EPSF);
        float om = 1.f - conf;
        atomicAdd(&corrP, -0.25f*om*om*logf(ptc));
        atomicAdd(&corrNP, 1u);
        float4 pb = bbox_pred[ia]; float4 m = st[bt];
        float ix1=fmaxf(pb.x,m.x), iy1=fmaxf(pb.y,m.y);
        float ix2=fminf(pb.z,m.z), iy2=fminf(pb.w,m.w);
        float inter=fmaxf(ix2-ix1,0.f)*fmaxf(iy2-iy1,0.f);
        float aa1=(pb.z-pb.x)*(pb.w-pb.y);
        float aa2=(m.z-m.x)*(m.w-m.y);
        float uni = aa1 + aa2 - inter;
        float iou = inter/(uni+EPSF);
        float ex1=fminf(pb.x,m.x), ey1=fminf(pb.y,m.y);
        float ex2=fmaxf(pb.z,m.z), ey2=fmaxf(pb.w,m.w);
        float enc=(ex2-ex1)*(ey2-ey1);
        float giou = iou - (enc-uni)/(enc+EPSF);
        float l1 = fabsf(pb.x-m.x)+fabsf(pb.y-m.y)+fabsf(pb.z-m.z)+fabsf(pb.w-m.w);
        atomicAdd(&corrB, (1.f - giou) + 0.125f*l1);
        if (mi < 0.4f) {                   // was counted negative in K1
          int bin = min(NBIN-1, (int)(conf*1024.f));
          atomicSub(&hhC[bin], 1u);
          atomicAdd(&hhF[bin], -focal_neg(conf));
          atomicAdd(&corrNN, 1u);
        }
      }
    }
  }
  __syncthreads();
  // ---- Phase E: partials wave-reduce (wave 0) ----
  if (tid < 64) {
    float ap = 0.f, ab = 0.f; unsigned np = 0, nn = 0;
    if (tid < nch) {
      int pidx = b*nch + tid;
      ap = accPosP[pidx]; ab = accBboxP[pidx];
      np = cntPosP[pidx]; nn = cntNegP[pidx];
    }
    for (int s = 1; s < 64; s <<= 1) {
      ap += __shfl_xor(ap, s, 64); ab += __shfl_xor(ab, s, 64);
      np += __shfl_xor(np, s, 64); nn += __shfl_xor(nn, s, 64);
    }
    if (tid == 0) {
      accPos_s  = ap + corrP;
      accBbox_s = ab + corrB;
      cntPos_s  = np + corrNP;
      cntNeg_s  = nn - corrNN;
    }
  }
  __syncthreads();
  // ---- Phase F: suffix count-scan -> selB/krem; hist-based negSum ----
  int np = (int)cntPos_s, nn = (int)cntNeg_s;
  int ratio = (np>0) ? min(3, A/np) : 0;
  int k = min(ratio*np, nn);
  float negSum = 0.f;
  if (k > 0) {
    sc[tid] = hhC[NBIN-1-tid];
    __syncthreads();
    for (int off=1; off<NBIN; off<<=1) {    // inclusive scan of reversed hist
      unsigned v = (tid >= off) ? sc[tid-off] : 0u;
      __syncthreads();
      sc[tid] += v;
      __syncthreads();
    }
    {
      unsigned Sb  = sc[NBIN-1-tid];
      unsigned Snx = (tid == NBIN-1) ? 0u : sc[NBIN-2-tid];
      if (Sb >= (unsigned)k && Snx < (unsigned)k) { sSelB = tid; sKrem = k - (int)Snx; }
    }
    __syncthreads();
    int selB = sSelB, krem = sKrem;
    sredf[tid] = (tid > selB) ? hhF[tid] : 0.f;
    __syncthreads();
    for (int s=512;s>0;s>>=1){ if(tid<s) sredf[tid]+=sredf[tid+s]; __syncthreads(); }
    float cutMean = hhF[selB] / (float)max(hhC[selB], 1u);  // hhC[selB] >= krem >= 1
    negSum = sredf[0] + (float)krem * cutMean;
  }
  if (tid==0) {
    float confL = (accPos_s + negSum) / (float)max(np + k, 1);
    float bboxL = accBbox_s / (float)(np > 0 ? np : 1);
    atomicAdd(out, (confL + bboxL) / (float)B);   // out zeroed by K1
  }
}

extern "C" void kernel_launch(void* const* d_in, const int* in_sizes, int n_in,
                              void* d_out, int out_size, void* d_ws, size_t ws_size,
                              hipStream_t stream) {
  const float4* bbox_pred = (const float4*)d_in[0];
  const float*  conf_pred = (const float*)d_in[1];
  const float4* anchors   = (const float4*)d_in[2];
  const float4* tboxes    = (const float4*)d_in[3];
  float* out = (float*)d_out;

  int A = in_sizes[2] / 4;          // 65536
  int B = in_sizes[1] / A;          // 16
  int T = in_sizes[3] / (4 * B);    // 32
  int nch = A / ACH;                // 64

  // ws: parts Part[B*T*nch] | ghsC u32[B*nch*NBIN] | ghsF f32[B*nch*NBIN] |
  //     accPosP f32[B*nch] | accBboxP f32[B*nch] | cntPosP u32[B*nch] | cntNegP u32[B*nch]
  Part* parts = (Part*)d_ws;
  unsigned* ghsC = (unsigned*)(parts + (size_t)B*T*nch);
  float* ghsF = (float*)(ghsC + (size_t)B*nch*NBIN);
  float* accPosP  = (float*)(ghsF + (size_t)B*nch*NBIN);
  float* accBboxP = accPosP + (size_t)B*nch;
  unsigned* cntPosP = (unsigned*)(accBboxP + (size_t)B*nch);
  unsigned* cntNegP = cntPosP + (size_t)B*nch;

  dim3 gf((unsigned)nch, (unsigned)B);
  k_fused<<<gf, 256, 0, stream>>>(anchors, tboxes, conf_pred, bbox_pred,
                                  parts, ghsC, ghsF,
                                  accPosP, accBboxP, cntPosP, cntNegP, out, A, T, nch);

  k_tail<<<B, 1024, 0, stream>>>(anchors, tboxes, parts, conf_pred, bbox_pred,
                                 ghsC, ghsF, accPosP, accBboxP, cntPosP, cntNegP,
                                 out, A, T, nch, B);
}